// Round 2
// 204.188 us; speedup vs baseline: 1.0192x; 1.0192x over previous
//
#include <hip/hip_runtime.h>

#define DM 128
#define NHEADS 8

typedef __attribute__((ext_vector_type(8))) __bf16 bf16x8;
typedef __attribute__((ext_vector_type(4))) float f32x4;

__device__ inline unsigned short f2bf(float f) {
    unsigned u = __float_as_uint(f);
    u += 0x7FFFu + ((u >> 16) & 1u);
    return (unsigned short)(u >> 16);
}

// ---------- prep: weight->bf16 conversion (blocks 0..63) + offset scan (block 64) ----------
__global__ void prep(const int* __restrict__ agents, int B,
                     const float* __restrict__ wqkv, const float* __restrict__ wout,
                     int* __restrict__ offs,
                     unsigned short* __restrict__ wqkv_bf,
                     unsigned short* __restrict__ wout_bf) {
    if (blockIdx.x < 64) {
        int idx = (blockIdx.x * 256 + threadIdx.x) * 4;   // 0..65532
        if (idx < 49152) {
            float4 v = *(const float4*)(wqkv + idx);
            ushort4 o;
            o.x = f2bf(v.x); o.y = f2bf(v.y); o.z = f2bf(v.z); o.w = f2bf(v.w);
            *(ushort4*)(wqkv_bf + idx) = o;
        } else {
            int j = idx - 49152;
            float4 v = *(const float4*)(wout + j);
            ushort4 o;
            o.x = f2bf(v.x); o.y = f2bf(v.y); o.z = f2bf(v.z); o.w = f2bf(v.w);
            *(ushort4*)(wout_bf + j) = o;
        }
    } else {
        __shared__ int part[256];
        const int tid = threadIdx.x;
        const int per = (B + 255) >> 8;
        const int base = tid * per;
        int s = 0;
        for (int i = 0; i < per; ++i) {
            int idx = base + i;
            if (idx < B) s += agents[idx];
        }
        part[tid] = s;
        __syncthreads();
        for (int off = 1; off < 256; off <<= 1) {
            int v = (tid >= off) ? part[tid - off] : 0;
            __syncthreads();
            part[tid] += v;
            __syncthreads();
        }
        int run = (tid == 0) ? 0 : part[tid - 1];
        for (int i = 0; i < per; ++i) {
            int idx = base + i;
            if (idx < B) { offs[idx] = run; run += agents[idx]; }
        }
    }
}

// ---------- kernel 1: qkv GEMM. 128-row strip/block; A in LDS; B prefetch-streamed from L2. ----------
// Operand-SWAPPED mfma: acc = mfma(B_frag, A_frag) -> each lane holds 4 consecutive
// output COLUMNS at a fixed row -> one ushort4 (8B) store per accumulator per ct
// (was: 8 scattered 2B stores per lane per ct -> store-issue-bound, MfmaUtil 4%).
__launch_bounds__(256, 4)
__global__ void qkv_gemm(const float* __restrict__ x,
                         const unsigned short* __restrict__ wqkvb,
                         const float* __restrict__ bqkv,
                         unsigned short* __restrict__ qws,   // [M][128] bf16
                         unsigned short* __restrict__ kv,    // [M][256] bf16 (K|V)
                         int M) {
    __shared__ __align__(16) unsigned short As[128 * 136];   // 34816 B
    const int m0 = blockIdx.x * 128;
    const int tid = threadIdx.x;

    for (int f = tid; f < 4096; f += 256) {          // A: 128 rows x 128 fp32 -> bf16 (zero pad)
        int t = f >> 5, c = f & 31;
        ushort4 o = make_ushort4(0, 0, 0, 0);
        if (m0 + t < M) {
            float4 v = ((const float4*)(x + (size_t)(m0 + t) * DM))[c];
            o.x = f2bf(v.x); o.y = f2bf(v.y); o.z = f2bf(v.z); o.w = f2bf(v.w);
        }
        *(ushort4*)&As[t * 136 + c * 4] = o;
    }
    __syncthreads();                                  // the ONLY barrier

    const int wave = tid >> 6, lane = tid & 63, quad = lane >> 4, l16 = lane & 15;
    const int mr = wave * 32;                         // each wave: 2 M-tiles (32 rows)
    bf16x8 af[2][4];
    #pragma unroll
    for (int mt = 0; mt < 2; ++mt)
        #pragma unroll
        for (int ks = 0; ks < 4; ++ks)
            af[mt][ks] = *(const bf16x8*)&As[(mr + mt * 16 + l16) * 136 + ks * 32 + quad * 8];

    // software pipeline: B-frags for ct+1 load while ct computes
    bf16x8 bp[4];
    #pragma unroll
    for (int ks = 0; ks < 4; ++ks)
        bp[ks] = *(const bf16x8*)(wqkvb + (size_t)l16 * DM + ks * 32 + quad * 8);

    const int row0 = m0 + mr + l16;                  // this lane's output row (acc0)
    const int row1 = row0 + 16;                      // acc1

    for (int ct = 0; ct < 24; ++ct) {
        bf16x8 bc[4];
        #pragma unroll
        for (int ks = 0; ks < 4; ++ks) bc[ks] = bp[ks];
        if (ct < 23) {
            const int gn = (ct + 1) * 16 + l16;
            #pragma unroll
            for (int ks = 0; ks < 4; ++ks)
                bp[ks] = *(const bf16x8*)(wqkvb + (size_t)gn * DM + ks * 32 + quad * 8);
        }
        // SWAPPED operands: D row-axis (regs) = n, D col-axis (lanes) = m
        f32x4 a0 = {0.f, 0.f, 0.f, 0.f}, a1 = {0.f, 0.f, 0.f, 0.f};
        #pragma unroll
        for (int ks = 0; ks < 4; ++ks) {
            a0 = __builtin_amdgcn_mfma_f32_16x16x32_bf16(bc[ks], af[0][ks], a0, 0, 0, 0);
            a1 = __builtin_amdgcn_mfma_f32_16x16x32_bf16(bc[ks], af[1][ks], a1, 0, 0, 0);
        }
        const int n0 = ct * 16 + quad * 4;           // 4 consecutive output cols
        const float4 b4 = *(const float4*)(bqkv + n0);
        ushort4 v0, v1;
        v0.x = f2bf(a0[0] + b4.x); v0.y = f2bf(a0[1] + b4.y);
        v0.z = f2bf(a0[2] + b4.z); v0.w = f2bf(a0[3] + b4.w);
        v1.x = f2bf(a1[0] + b4.x); v1.y = f2bf(a1[1] + b4.y);
        v1.z = f2bf(a1[2] + b4.z); v1.w = f2bf(a1[3] + b4.w);
        if (n0 < 128) {                              // Q stripe
            if (row0 < M) *(ushort4*)(qws + (size_t)row0 * 128 + n0) = v0;
            if (row1 < M) *(ushort4*)(qws + (size_t)row1 * 128 + n0) = v1;
        } else {                                     // K stripe (n0<256) and V stripe share: col = n0-128
            const int c = n0 - 128;
            if (row0 < M) *(ushort4*)(kv + (size_t)row0 * 256 + c) = v0;
            if (row1 < M) *(ushort4*)(kv + (size_t)row1 * 256 + c) = v1;
        }
    }
}

// ---------- kernel 2: attention. 1 block/sample, 8 waves (1/head). ----------
// LDS: Ks[64][136] | Vs[64][136] (row-major!) | Ps[8][16][72] = 53248 B -> 3 blocks/CU
// Q is NOT staged: each wave loads its Q fragments directly from global (L2-hot).
#define KS_OFF 0
#define VS_OFF 17408
#define PS_OFF 34816
#define SMEM2 53248

__launch_bounds__(512, 6)
__global__ void attn(unsigned short* __restrict__ qa,       // in: Q [M][128]; out: attn (same buf)
                     const unsigned short* __restrict__ kv, // [M][256] K|V
                     const int* __restrict__ agents,
                     const int* __restrict__ offs,
                     int M) {
    __shared__ __align__(16) char smem[SMEM2];
    unsigned short* Ks = (unsigned short*)(smem + KS_OFF);
    unsigned short* Vs = (unsigned short*)(smem + VS_OFF);
    unsigned short* Ps = (unsigned short*)(smem + PS_OFF);

    const int s = blockIdx.x;
    const int n = agents[s];
    const int base = offs[s];
    const int tid = threadIdx.x;
    const int wave = tid >> 6, lane = tid & 63, quad = lane >> 4, l16 = lane & 15;
    const int h = wave;                      // one wave per head
    const int nkt = (n + 15) >> 4;           // 16-key tiles
    const int nks = (n + 31) >> 5;           // 32-key groups

    // zero ENTIRE smem (R8 rule: every LDS byte an MFMA can touch gets zeroed)
    for (int f = tid; f < 3328; f += 512)
        ((uint4*)smem)[f] = make_uint4(0u, 0u, 0u, 0u);
    __syncthreads();

    // stage K and V rows, both row-major (coalesced uint4; no transpose scatter)
    for (int f = tid; f < n * 16; f += 512) {
        int t = f >> 4, c = f & 15;
        *(uint4*)&Ks[t * 136 + c * 8] = *(const uint4*)(kv + (size_t)(base + t) * 256 + c * 8);
        *(uint4*)&Vs[t * 136 + c * 8] = *(const uint4*)(kv + (size_t)(base + t) * 256 + 128 + c * 8);
    }
    __syncthreads();

    unsigned short* Pw = Ps + wave * 16 * 72;
    const __bf16* Vsb = (const __bf16*)Vs;
    for (int mt = 0; mt < nkt; ++mt) {       // query tiles
        // Q fragment direct from global (A-layout, head_dim 16 zero-padded to K=32).
        // Row clamped to M-1: clamped/raced rows are finite and only feed discarded outputs.
        bf16x8 qf = (bf16x8)(__bf16)0.0f;
        if (quad < 2) {
            int qrow = base + mt * 16 + l16;
            qrow = (qrow < M) ? qrow : (M - 1);
            qf = *(const bf16x8*)(qa + (size_t)qrow * 128 + h * 16 + quad * 8);
        }
        f32x4 sc[4];
        #pragma unroll
        for (int kt = 0; kt < 4; ++kt)
            sc[kt] = (f32x4){0.f, 0.f, 0.f, 0.f};
        #pragma unroll
        for (int kt = 0; kt < 4; ++kt) {
            if (kt < nkt) {
                bf16x8 bb = *(const bf16x8*)&Ks[(kt * 16 + l16) * 136 + h * 16 + quad * 8];
                sc[kt] = __builtin_amdgcn_mfma_f32_16x16x32_bf16(qf, bb,
                          (f32x4){0.f, 0.f, 0.f, 0.f}, 0, 0, 0);
            }
        }
        #pragma unroll
        for (int r = 0; r < 4; ++r) {
            float pr[4];
            float mm = -1e30f;
            #pragma unroll
            for (int kt = 0; kt < 4; ++kt) {
                float v = -1e30f;
                if (kt < nkt) {
                    int key = kt * 16 + l16;
                    v = (key < n) ? sc[kt][r] * 0.25f : -1e30f;   // scale = 1/sqrt(16)
                }
                pr[kt] = v;
                mm = fmaxf(mm, v);
            }
            mm = fmaxf(mm, __shfl_xor(mm, 1));
            mm = fmaxf(mm, __shfl_xor(mm, 2));
            mm = fmaxf(mm, __shfl_xor(mm, 4));
            mm = fmaxf(mm, __shfl_xor(mm, 8));
            float ll = 0.f;
            #pragma unroll
            for (int kt = 0; kt < 4; ++kt) {
                if (kt < nkt) {
                    float e = __expf(pr[kt] - mm);
                    pr[kt] = e;
                    ll += e;
                }
            }
            ll += __shfl_xor(ll, 1);
            ll += __shfl_xor(ll, 2);
            ll += __shfl_xor(ll, 4);
            ll += __shfl_xor(ll, 8);
            float inv = 1.0f / ll;
            #pragma unroll
            for (int kt = 0; kt < 4; ++kt)
                if (kt < nkt)
                    Pw[(quad * 4 + r) * 72 + kt * 16 + l16] = f2bf(pr[kt] * inv);
        }
        // PV: A = P (wave-private), B built from row-major Vs by 8 scalar LDS reads:
        // B element (k=quad*8+j, n=l16) = V[tok=ks2*32+quad*8+j][d=h*16+l16]
        f32x4 o = {0.f, 0.f, 0.f, 0.f};
        #pragma unroll
        for (int ks2 = 0; ks2 < 2; ++ks2) {
            if (ks2 < nks) {
                bf16x8 a = *(const bf16x8*)&Pw[l16 * 72 + ks2 * 32 + quad * 8];
                bf16x8 bb;
                #pragma unroll
                for (int j = 0; j < 8; ++j)
                    bb[j] = Vsb[(ks2 * 32 + quad * 8 + j) * 136 + h * 16 + l16];
                o = __builtin_amdgcn_mfma_f32_16x16x32_bf16(a, bb, o, 0, 0, 0);
            }
        }
        #pragma unroll
        for (int r = 0; r < 4; ++r) {
            int row = mt * 16 + quad * 4 + r;
            if (row < n)
                qa[(size_t)(base + row) * 128 + h * 16 + l16] = f2bf(o[r]);
        }
    }
}

// ---------- kernel 3: out-proj GEMM. 128-row strip/block; Wout prefetch-streamed. ----------
// Same swapped-operand epilogue: one float4 (16B) store per accumulator per ct.
__launch_bounds__(256, 4)
__global__ void oproj(const unsigned short* __restrict__ attn_b,  // [M][128] bf16 (ws)
                      const unsigned short* __restrict__ woutb,
                      const float* __restrict__ bout,
                      float* __restrict__ out, int M) {
    __shared__ __align__(16) unsigned short As[128 * 136];
    const int m0 = blockIdx.x * 128;
    const int tid = threadIdx.x;

    for (int f = tid; f < 2048; f += 256) {          // A tile (zero pad beyond M)
        int t = f >> 4, c = f & 15;
        uint4 w = make_uint4(0u, 0u, 0u, 0u);
        if (m0 + t < M)
            w = *(const uint4*)(attn_b + (size_t)(m0 + t) * DM + c * 8);
        *(uint4*)&As[t * 136 + c * 8] = w;
    }
    __syncthreads();                                  // the ONLY barrier

    const int wave = tid >> 6, lane = tid & 63, quad = lane >> 4, l16 = lane & 15;
    const int mr = wave * 32;
    bf16x8 af[2][4];
    #pragma unroll
    for (int mt = 0; mt < 2; ++mt)
        #pragma unroll
        for (int ks = 0; ks < 4; ++ks)
            af[mt][ks] = *(const bf16x8*)&As[(mr + mt * 16 + l16) * 136 + ks * 32 + quad * 8];

    bf16x8 bp[4];
    #pragma unroll
    for (int ks = 0; ks < 4; ++ks)
        bp[ks] = *(const bf16x8*)(woutb + (size_t)l16 * DM + ks * 32 + quad * 8);

    const int row0 = m0 + mr + l16;
    const int row1 = row0 + 16;

    for (int ct = 0; ct < 8; ++ct) {
        bf16x8 bc[4];
        #pragma unroll
        for (int ks = 0; ks < 4; ++ks) bc[ks] = bp[ks];
        if (ct < 7) {
            const int gn = (ct + 1) * 16 + l16;
            #pragma unroll
            for (int ks = 0; ks < 4; ++ks)
                bp[ks] = *(const bf16x8*)(woutb + (size_t)gn * DM + ks * 32 + quad * 8);
        }
        // SWAPPED operands: lanes = rows (m), regs = 4 consecutive cols (n)
        f32x4 a0 = {0.f, 0.f, 0.f, 0.f}, a1 = {0.f, 0.f, 0.f, 0.f};
        #pragma unroll
        for (int ks = 0; ks < 4; ++ks) {
            a0 = __builtin_amdgcn_mfma_f32_16x16x32_bf16(bc[ks], af[0][ks], a0, 0, 0, 0);
            a1 = __builtin_amdgcn_mfma_f32_16x16x32_bf16(bc[ks], af[1][ks], a1, 0, 0, 0);
        }
        const int n0 = ct * 16 + quad * 4;
        const float4 b4 = *(const float4*)(bout + n0);
        float4 o0, o1;
        o0.x = a0[0] + b4.x; o0.y = a0[1] + b4.y; o0.z = a0[2] + b4.z; o0.w = a0[3] + b4.w;
        o1.x = a1[0] + b4.x; o1.y = a1[1] + b4.y; o1.z = a1[2] + b4.z; o1.w = a1[3] + b4.w;
        if (row0 < M) *(float4*)(out + (size_t)row0 * DM + n0) = o0;
        if (row1 < M) *(float4*)(out + (size_t)row1 * DM + n0) = o1;
    }
}

extern "C" void kernel_launch(void* const* d_in, const int* in_sizes, int n_in,
                              void* d_out, int out_size, void* d_ws, size_t ws_size,
                              hipStream_t stream) {
    const float* att_in     = (const float*)d_in[0];
    const float* in_proj_w  = (const float*)d_in[1];
    const float* in_proj_b  = (const float*)d_in[2];
    const float* out_proj_w = (const float*)d_in[3];
    const float* out_proj_b = (const float*)d_in[4];
    const int*   agents     = (const int*)d_in[5];
    const int B = in_sizes[5];
    const int M = out_size / DM;             // total tokens (66560)

    // ws layout (assumes ws_size >= ~17.2 MB):
    //   [0,8192)            offs
    //   [8192,106496)       wqkv bf16
    //   [106496,139264)     wout bf16
    //   [139264, +M*256)    Q bf16, later attn_out bf16 (overwritten in-place by attn)
    int* offs = (int*)d_ws;
    unsigned short* wqkv_bf = (unsigned short*)((char*)d_ws + 8192);
    unsigned short* wout_bf = (unsigned short*)((char*)d_ws + 106496);
    unsigned short* qbuf    = (unsigned short*)((char*)d_ws + 139264);
    unsigned short* kvbuf   = (unsigned short*)d_out;   // [M][256] bf16 == exactly out bytes

    hipLaunchKernelGGL(prep, dim3(65), dim3(256), 0, stream,
                       agents, B, in_proj_w, out_proj_w, offs, wqkv_bf, wout_bf);
    hipLaunchKernelGGL(qkv_gemm, dim3((M + 127) / 128), dim3(256), 0, stream,
                       att_in, wqkv_bf, in_proj_b, qbuf, kvbuf, M);
    hipLaunchKernelGGL(attn, dim3(B), dim3(512), 0, stream,
                       qbuf, kvbuf, agents, offs, M);
    hipLaunchKernelGGL(oproj, dim3((M + 127) / 128), dim3(256), 0, stream,
                       qbuf, wout_bf, out_proj_b, (float*)d_out, M);
}

// Round 3
// 176.804 us; speedup vs baseline: 1.1770x; 1.1549x over previous
//
#include <hip/hip_runtime.h>

#define DM 128
#define NHEADS 8

typedef __attribute__((ext_vector_type(8))) __bf16 bf16x8;
typedef __attribute__((ext_vector_type(8))) unsigned short u16x8;
typedef __attribute__((ext_vector_type(4))) float f32x4;

__device__ inline unsigned short f2bf(float f) {
    unsigned u = __float_as_uint(f);
    u += 0x7FFFu + ((u >> 16) & 1u);
    return (unsigned short)(u >> 16);
}

// ---------- prep: weight->bf16 conversion (blocks 0..63) + offset scan (block 64) ----------
__global__ void prep(const int* __restrict__ agents, int B,
                     const float* __restrict__ wqkv, const float* __restrict__ wout,
                     int* __restrict__ offs,
                     unsigned short* __restrict__ wqkv_bf,
                     unsigned short* __restrict__ wout_bf) {
    if (blockIdx.x < 64) {
        int idx = (blockIdx.x * 256 + threadIdx.x) * 4;   // 0..65532
        if (idx < 49152) {
            float4 v = *(const float4*)(wqkv + idx);
            ushort4 o;
            o.x = f2bf(v.x); o.y = f2bf(v.y); o.z = f2bf(v.z); o.w = f2bf(v.w);
            *(ushort4*)(wqkv_bf + idx) = o;
        } else {
            int j = idx - 49152;
            float4 v = *(const float4*)(wout + j);
            ushort4 o;
            o.x = f2bf(v.x); o.y = f2bf(v.y); o.z = f2bf(v.z); o.w = f2bf(v.w);
            *(ushort4*)(wout_bf + j) = o;
        }
    } else {
        __shared__ int part[256];
        const int tid = threadIdx.x;
        const int per = (B + 255) >> 8;
        const int base = tid * per;
        int s = 0;
        for (int i = 0; i < per; ++i) {
            int idx = base + i;
            if (idx < B) s += agents[idx];
        }
        part[tid] = s;
        __syncthreads();
        for (int off = 1; off < 256; off <<= 1) {
            int v = (tid >= off) ? part[tid - off] : 0;
            __syncthreads();
            part[tid] += v;
            __syncthreads();
        }
        int run = (tid == 0) ? 0 : part[tid - 1];
        for (int i = 0; i < per; ++i) {
            int idx = base + i;
            if (idx < B) { offs[idx] = run; run += agents[idx]; }
        }
    }
}

// ---------- kernel 1: qkv GEMM, v2 (weight-stationary-in-LDS, store-decoupled) ----------
// One block = one 128-row strip x one 128-col SEGMENT (seg 0=Q, 1=K, 2=V).
// Weight slice + bias staged in LDS once; A streamed into registers once per wave.
// Inner loop = ds_read (lgkmcnt) + MFMA + stores only: stores (vmcnt) can NEVER
// gate operand reads (the round-0/1 58us plateau was in-order vmcnt retirement
// chaining each iteration's B-load wait behind prior store drain).
// grid = 3*strips = 1560 -> 4 blocks/CU (LDS 35KB), 16 waves/CU (2x the old 8).
__launch_bounds__(256, 4)
__global__ void qkv_gemm(const float* __restrict__ x,
                         const unsigned short* __restrict__ wqkvb,
                         const float* __restrict__ bqkv,
                         unsigned short* __restrict__ qws,   // [M][128] bf16
                         unsigned short* __restrict__ kv,    // [M][256] bf16 (K|V)
                         int M) {
    __shared__ __align__(16) unsigned short Bs[128 * 136];   // 34816 B
    __shared__ __align__(16) float biass[128];
    const int bid = blockIdx.x;
    const int seg = bid % 3;             // 0:Q 1:K 2:V (weight rows seg*128..+127)
    const int m0 = (bid / 3) * 128;
    const int tid = threadIdx.x;

    // stage weight slice [128][128] bf16 -> LDS (coalesced uint4)
    for (int f = tid; f < 2048; f += 256) {
        int t = f >> 4, c = f & 15;
        *(uint4*)&Bs[t * 136 + c * 8] =
            *(const uint4*)(wqkvb + (size_t)(seg * 128 + t) * 128 + c * 8);
    }
    if (tid < 32)
        ((float4*)biass)[tid] = ((const float4*)(bqkv + seg * 128))[tid];
    __syncthreads();                                  // the ONLY barrier

    const int wave = tid >> 6, lane = tid & 63, quad = lane >> 4, l16 = lane & 15;
    const int mw = m0 + wave * 32;                    // each wave: 32 rows (2 M-tiles)

    // A: 32 rows x 128 fp32 -> bf16 frags, straight to registers (no LDS, no barrier).
    // This is the only global-load burst in the wave; it precedes every store.
    bf16x8 af[2][4];
    #pragma unroll
    for (int mt = 0; mt < 2; ++mt) {
        int row = mw + mt * 16 + l16;
        row = (row < M) ? row : (M - 1);              // clamp (grid covers M exactly)
        const float* xr = x + (size_t)row * DM;
        #pragma unroll
        for (int ks = 0; ks < 4; ++ks) {
            float4 u = *(const float4*)(xr + ks * 32 + quad * 8);
            float4 v = *(const float4*)(xr + ks * 32 + quad * 8 + 4);
            u16x8 t;
            t[0] = f2bf(u.x); t[1] = f2bf(u.y); t[2] = f2bf(u.z); t[3] = f2bf(u.w);
            t[4] = f2bf(v.x); t[5] = f2bf(v.y); t[6] = f2bf(v.z); t[7] = f2bf(v.w);
            af[mt][ks] = __builtin_bit_cast(bf16x8, t);
        }
    }

    // wave-uniform output routing
    unsigned short* obase; int ostride, ocol;
    if (seg == 0) { obase = qws; ostride = 128; ocol = 0; }
    else          { obase = kv;  ostride = 256; ocol = (seg == 2) ? 128 : 0; }

    const int row0 = mw + l16, row1 = row0 + 16;

    for (int ct = 0; ct < 8; ++ct) {
        bf16x8 bc[4];
        #pragma unroll
        for (int ks = 0; ks < 4; ++ks)
            bc[ks] = *(const bf16x8*)&Bs[(ct * 16 + l16) * 136 + ks * 32 + quad * 8];
        // SWAPPED operands: D row-axis (regs) = n, D col-axis (lanes) = m
        f32x4 a0 = {0.f, 0.f, 0.f, 0.f}, a1 = {0.f, 0.f, 0.f, 0.f};
        #pragma unroll
        for (int ks = 0; ks < 4; ++ks) {
            a0 = __builtin_amdgcn_mfma_f32_16x16x32_bf16(bc[ks], af[0][ks], a0, 0, 0, 0);
            a1 = __builtin_amdgcn_mfma_f32_16x16x32_bf16(bc[ks], af[1][ks], a1, 0, 0, 0);
        }
        const int n0 = ct * 16 + quad * 4;            // 4 consecutive cols (within segment)
        const float4 b4 = *(const float4*)(biass + n0);  // LDS read (lgkmcnt)
        ushort4 v0, v1;
        v0.x = f2bf(a0[0] + b4.x); v0.y = f2bf(a0[1] + b4.y);
        v0.z = f2bf(a0[2] + b4.z); v0.w = f2bf(a0[3] + b4.w);
        v1.x = f2bf(a1[0] + b4.x); v1.y = f2bf(a1[1] + b4.y);
        v1.z = f2bf(a1[2] + b4.z); v1.w = f2bf(a1[3] + b4.w);
        if (row0 < M) *(ushort4*)(obase + (size_t)row0 * ostride + ocol + n0) = v0;
        if (row1 < M) *(ushort4*)(obase + (size_t)row1 * ostride + ocol + n0) = v1;
    }
}

// ---------- kernel 2: attention. 1 block/sample, 8 waves (1/head). (unchanged) ----------
#define KS_OFF 0
#define VS_OFF 17408
#define PS_OFF 34816
#define SMEM2 53248

__launch_bounds__(512, 6)
__global__ void attn(unsigned short* __restrict__ qa,       // in: Q [M][128]; out: attn (same buf)
                     const unsigned short* __restrict__ kv, // [M][256] K|V
                     const int* __restrict__ agents,
                     const int* __restrict__ offs,
                     int M) {
    __shared__ __align__(16) char smem[SMEM2];
    unsigned short* Ks = (unsigned short*)(smem + KS_OFF);
    unsigned short* Vs = (unsigned short*)(smem + VS_OFF);
    unsigned short* Ps = (unsigned short*)(smem + PS_OFF);

    const int s = blockIdx.x;
    const int n = agents[s];
    const int base = offs[s];
    const int tid = threadIdx.x;
    const int wave = tid >> 6, lane = tid & 63, quad = lane >> 4, l16 = lane & 15;
    const int h = wave;                      // one wave per head
    const int nkt = (n + 15) >> 4;           // 16-key tiles
    const int nks = (n + 31) >> 5;           // 32-key groups

    for (int f = tid; f < 3328; f += 512)
        ((uint4*)smem)[f] = make_uint4(0u, 0u, 0u, 0u);
    __syncthreads();

    for (int f = tid; f < n * 16; f += 512) {
        int t = f >> 4, c = f & 15;
        *(uint4*)&Ks[t * 136 + c * 8] = *(const uint4*)(kv + (size_t)(base + t) * 256 + c * 8);
        *(uint4*)&Vs[t * 136 + c * 8] = *(const uint4*)(kv + (size_t)(base + t) * 256 + 128 + c * 8);
    }
    __syncthreads();

    unsigned short* Pw = Ps + wave * 16 * 72;
    const __bf16* Vsb = (const __bf16*)Vs;
    for (int mt = 0; mt < nkt; ++mt) {       // query tiles
        bf16x8 qf = (bf16x8)(__bf16)0.0f;
        if (quad < 2) {
            int qrow = base + mt * 16 + l16;
            qrow = (qrow < M) ? qrow : (M - 1);
            qf = *(const bf16x8*)(qa + (size_t)qrow * 128 + h * 16 + quad * 8);
        }
        f32x4 sc[4];
        #pragma unroll
        for (int kt = 0; kt < 4; ++kt)
            sc[kt] = (f32x4){0.f, 0.f, 0.f, 0.f};
        #pragma unroll
        for (int kt = 0; kt < 4; ++kt) {
            if (kt < nkt) {
                bf16x8 bb = *(const bf16x8*)&Ks[(kt * 16 + l16) * 136 + h * 16 + quad * 8];
                sc[kt] = __builtin_amdgcn_mfma_f32_16x16x32_bf16(qf, bb,
                          (f32x4){0.f, 0.f, 0.f, 0.f}, 0, 0, 0);
            }
        }
        #pragma unroll
        for (int r = 0; r < 4; ++r) {
            float pr[4];
            float mm = -1e30f;
            #pragma unroll
            for (int kt = 0; kt < 4; ++kt) {
                float v = -1e30f;
                if (kt < nkt) {
                    int key = kt * 16 + l16;
                    v = (key < n) ? sc[kt][r] * 0.25f : -1e30f;   // scale = 1/sqrt(16)
                }
                pr[kt] = v;
                mm = fmaxf(mm, v);
            }
            mm = fmaxf(mm, __shfl_xor(mm, 1));
            mm = fmaxf(mm, __shfl_xor(mm, 2));
            mm = fmaxf(mm, __shfl_xor(mm, 4));
            mm = fmaxf(mm, __shfl_xor(mm, 8));
            float ll = 0.f;
            #pragma unroll
            for (int kt = 0; kt < 4; ++kt) {
                if (kt < nkt) {
                    float e = __expf(pr[kt] - mm);
                    pr[kt] = e;
                    ll += e;
                }
            }
            ll += __shfl_xor(ll, 1);
            ll += __shfl_xor(ll, 2);
            ll += __shfl_xor(ll, 4);
            ll += __shfl_xor(ll, 8);
            float inv = 1.0f / ll;
            #pragma unroll
            for (int kt = 0; kt < 4; ++kt)
                if (kt < nkt)
                    Pw[(quad * 4 + r) * 72 + kt * 16 + l16] = f2bf(pr[kt] * inv);
        }
        f32x4 o = {0.f, 0.f, 0.f, 0.f};
        #pragma unroll
        for (int ks2 = 0; ks2 < 2; ++ks2) {
            if (ks2 < nks) {
                bf16x8 a = *(const bf16x8*)&Pw[l16 * 72 + ks2 * 32 + quad * 8];
                bf16x8 bb;
                #pragma unroll
                for (int j = 0; j < 8; ++j)
                    bb[j] = Vsb[(ks2 * 32 + quad * 8 + j) * 136 + h * 16 + l16];
                o = __builtin_amdgcn_mfma_f32_16x16x32_bf16(a, bb, o, 0, 0, 0);
            }
        }
        #pragma unroll
        for (int r = 0; r < 4; ++r) {
            int row = mt * 16 + quad * 4 + r;
            if (row < n)
                qa[(size_t)(base + row) * 128 + h * 16 + l16] = f2bf(o[r]);
        }
    }
}

// ---------- kernel 3: out-proj GEMM, v2 (Wout+bias in LDS, store-decoupled) ----------
// 64-row blocks (4 waves x 16 rows) -> grid 1040 -> 4 blocks/CU, 16 waves/CU.
// A (attn output) already bf16: 4 direct frag loads per wave, no conversion.
__launch_bounds__(256, 4)
__global__ void oproj(const unsigned short* __restrict__ attn_b,  // [M][128] bf16 (ws)
                      const unsigned short* __restrict__ woutb,
                      const float* __restrict__ bout,
                      float* __restrict__ out, int M) {
    __shared__ __align__(16) unsigned short Ws[128 * 136];   // 34816 B
    __shared__ __align__(16) float biass[128];
    const int m0 = blockIdx.x * 64;
    const int tid = threadIdx.x;

    for (int f = tid; f < 2048; f += 256) {          // Wout [128][128] bf16 -> LDS
        int t = f >> 4, c = f & 15;
        *(uint4*)&Ws[t * 136 + c * 8] = *(const uint4*)(woutb + (size_t)t * 128 + c * 8);
    }
    if (tid < 32)
        ((float4*)biass)[tid] = ((const float4*)bout)[tid];
    __syncthreads();                                  // the ONLY barrier

    const int wave = tid >> 6, lane = tid & 63, quad = lane >> 4, l16 = lane & 15;
    const int mw = m0 + wave * 16;                   // each wave: 16 rows

    bf16x8 af[4];
    {
        int row = mw + l16;
        row = (row < M) ? row : (M - 1);
        #pragma unroll
        for (int ks = 0; ks < 4; ++ks)
            af[ks] = *(const bf16x8*)(attn_b + (size_t)row * DM + ks * 32 + quad * 8);
    }

    const int row0 = mw + l16;

    for (int ct = 0; ct < 8; ++ct) {
        bf16x8 bc[4];
        #pragma unroll
        for (int ks = 0; ks < 4; ++ks)
            bc[ks] = *(const bf16x8*)&Ws[(ct * 16 + l16) * 136 + ks * 32 + quad * 8];
        // SWAPPED operands: lanes = rows (m), regs = 4 consecutive cols (n)
        f32x4 a0 = {0.f, 0.f, 0.f, 0.f};
        #pragma unroll
        for (int ks = 0; ks < 4; ++ks)
            a0 = __builtin_amdgcn_mfma_f32_16x16x32_bf16(bc[ks], af[ks], a0, 0, 0, 0);
        const int n0 = ct * 16 + quad * 4;
        const float4 b4 = *(const float4*)(biass + n0);
        float4 o0;
        o0.x = a0[0] + b4.x; o0.y = a0[1] + b4.y; o0.z = a0[2] + b4.z; o0.w = a0[3] + b4.w;
        if (row0 < M) *(float4*)(out + (size_t)row0 * DM + n0) = o0;
    }
}

extern "C" void kernel_launch(void* const* d_in, const int* in_sizes, int n_in,
                              void* d_out, int out_size, void* d_ws, size_t ws_size,
                              hipStream_t stream) {
    const float* att_in     = (const float*)d_in[0];
    const float* in_proj_w  = (const float*)d_in[1];
    const float* in_proj_b  = (const float*)d_in[2];
    const float* out_proj_w = (const float*)d_in[3];
    const float* out_proj_b = (const float*)d_in[4];
    const int*   agents     = (const int*)d_in[5];
    const int B = in_sizes[5];
    const int M = out_size / DM;             // total tokens (66560)

    // ws layout (assumes ws_size >= ~17.2 MB):
    //   [0,8192)            offs
    //   [8192,106496)       wqkv bf16
    //   [106496,139264)     wout bf16
    //   [139264, +M*256)    Q bf16, later attn_out bf16 (overwritten in-place by attn)
    int* offs = (int*)d_ws;
    unsigned short* wqkv_bf = (unsigned short*)((char*)d_ws + 8192);
    unsigned short* wout_bf = (unsigned short*)((char*)d_ws + 106496);
    unsigned short* qbuf    = (unsigned short*)((char*)d_ws + 139264);
    unsigned short* kvbuf   = (unsigned short*)d_out;   // [M][256] bf16 == exactly out bytes

    const int strips = (M + 127) / 128;

    hipLaunchKernelGGL(prep, dim3(65), dim3(256), 0, stream,
                       agents, B, in_proj_w, out_proj_w, offs, wqkv_bf, wout_bf);
    hipLaunchKernelGGL(qkv_gemm, dim3(strips * 3), dim3(256), 0, stream,
                       att_in, wqkv_bf, in_proj_b, qbuf, kvbuf, M);
    hipLaunchKernelGGL(attn, dim3(B), dim3(512), 0, stream,
                       qbuf, kvbuf, agents, offs, M);
    hipLaunchKernelGGL(oproj, dim3((M + 63) / 64), dim3(256), 0, stream,
                       qbuf, wout_bf, out_proj_b, (float*)d_out, M);
}

// Round 4
// 158.997 us; speedup vs baseline: 1.3088x; 1.1120x over previous
//
#include <hip/hip_runtime.h>

#define DM 128
#define NHEADS 8

typedef __attribute__((ext_vector_type(8))) __bf16 bf16x8;
typedef __attribute__((ext_vector_type(8))) unsigned short u16x8;
typedef __attribute__((ext_vector_type(4))) float f32x4;

__device__ inline unsigned short f2bf(float f) {
    unsigned u = __float_as_uint(f);
    u += 0x7FFFu + ((u >> 16) & 1u);
    return (unsigned short)(u >> 16);
}

// ---------- prep: weight->bf16 conversion (blocks 0..63) + offset scan (block 64) ----------
__global__ void prep(const int* __restrict__ agents, int B,
                     const float* __restrict__ wqkv, const float* __restrict__ wout,
                     int* __restrict__ offs,
                     unsigned short* __restrict__ wqkv_bf,
                     unsigned short* __restrict__ wout_bf) {
    if (blockIdx.x < 64) {
        int idx = (blockIdx.x * 256 + threadIdx.x) * 4;   // 0..65532
        if (idx < 49152) {
            float4 v = *(const float4*)(wqkv + idx);
            ushort4 o;
            o.x = f2bf(v.x); o.y = f2bf(v.y); o.z = f2bf(v.z); o.w = f2bf(v.w);
            *(ushort4*)(wqkv_bf + idx) = o;
        } else {
            int j = idx - 49152;
            float4 v = *(const float4*)(wout + j);
            ushort4 o;
            o.x = f2bf(v.x); o.y = f2bf(v.y); o.z = f2bf(v.z); o.w = f2bf(v.w);
            *(ushort4*)(wout_bf + j) = o;
        }
    } else {
        __shared__ int part[256];
        const int tid = threadIdx.x;
        const int per = (B + 255) >> 8;
        const int base = tid * per;
        int s = 0;
        for (int i = 0; i < per; ++i) {
            int idx = base + i;
            if (idx < B) s += agents[idx];
        }
        part[tid] = s;
        __syncthreads();
        for (int off = 1; off < 256; off <<= 1) {
            int v = (tid >= off) ? part[tid - off] : 0;
            __syncthreads();
            part[tid] += v;
            __syncthreads();
        }
        int run = (tid == 0) ? 0 : part[tid - 1];
        for (int i = 0; i < per; ++i) {
            int idx = base + i;
            if (idx < B) { offs[idx] = run; run += agents[idx]; }
        }
    }
}

// ---------- kernel 1: qkv GEMM (unchanged from round 3) ----------
__launch_bounds__(256, 4)
__global__ void qkv_gemm(const float* __restrict__ x,
                         const unsigned short* __restrict__ wqkvb,
                         const float* __restrict__ bqkv,
                         unsigned short* __restrict__ qws,   // [M][128] bf16
                         unsigned short* __restrict__ kv,    // [M][256] bf16 (K|V)
                         int M) {
    __shared__ __align__(16) unsigned short Bs[128 * 136];   // 34816 B
    __shared__ __align__(16) float biass[128];
    const int bid = blockIdx.x;
    const int seg = bid % 3;             // 0:Q 1:K 2:V (weight rows seg*128..+127)
    const int m0 = (bid / 3) * 128;
    const int tid = threadIdx.x;

    for (int f = tid; f < 2048; f += 256) {
        int t = f >> 4, c = f & 15;
        *(uint4*)&Bs[t * 136 + c * 8] =
            *(const uint4*)(wqkvb + (size_t)(seg * 128 + t) * 128 + c * 8);
    }
    if (tid < 32)
        ((float4*)biass)[tid] = ((const float4*)(bqkv + seg * 128))[tid];
    __syncthreads();                                  // the ONLY barrier

    const int wave = tid >> 6, lane = tid & 63, quad = lane >> 4, l16 = lane & 15;
    const int mw = m0 + wave * 32;                    // each wave: 32 rows (2 M-tiles)

    bf16x8 af[2][4];
    #pragma unroll
    for (int mt = 0; mt < 2; ++mt) {
        int row = mw + mt * 16 + l16;
        row = (row < M) ? row : (M - 1);
        const float* xr = x + (size_t)row * DM;
        #pragma unroll
        for (int ks = 0; ks < 4; ++ks) {
            float4 u = *(const float4*)(xr + ks * 32 + quad * 8);
            float4 v = *(const float4*)(xr + ks * 32 + quad * 8 + 4);
            u16x8 t;
            t[0] = f2bf(u.x); t[1] = f2bf(u.y); t[2] = f2bf(u.z); t[3] = f2bf(u.w);
            t[4] = f2bf(v.x); t[5] = f2bf(v.y); t[6] = f2bf(v.z); t[7] = f2bf(v.w);
            af[mt][ks] = __builtin_bit_cast(bf16x8, t);
        }
    }

    unsigned short* obase; int ostride, ocol;
    if (seg == 0) { obase = qws; ostride = 128; ocol = 0; }
    else          { obase = kv;  ostride = 256; ocol = (seg == 2) ? 128 : 0; }

    const int row0 = mw + l16, row1 = row0 + 16;

    for (int ct = 0; ct < 8; ++ct) {
        bf16x8 bc[4];
        #pragma unroll
        for (int ks = 0; ks < 4; ++ks)
            bc[ks] = *(const bf16x8*)&Bs[(ct * 16 + l16) * 136 + ks * 32 + quad * 8];
        f32x4 a0 = {0.f, 0.f, 0.f, 0.f}, a1 = {0.f, 0.f, 0.f, 0.f};
        #pragma unroll
        for (int ks = 0; ks < 4; ++ks) {
            a0 = __builtin_amdgcn_mfma_f32_16x16x32_bf16(bc[ks], af[0][ks], a0, 0, 0, 0);
            a1 = __builtin_amdgcn_mfma_f32_16x16x32_bf16(bc[ks], af[1][ks], a1, 0, 0, 0);
        }
        const int n0 = ct * 16 + quad * 4;
        const float4 b4 = *(const float4*)(biass + n0);
        ushort4 v0, v1;
        v0.x = f2bf(a0[0] + b4.x); v0.y = f2bf(a0[1] + b4.y);
        v0.z = f2bf(a0[2] + b4.z); v0.w = f2bf(a0[3] + b4.w);
        v1.x = f2bf(a1[0] + b4.x); v1.y = f2bf(a1[1] + b4.y);
        v1.z = f2bf(a1[2] + b4.z); v1.w = f2bf(a1[3] + b4.w);
        if (row0 < M) *(ushort4*)(obase + (size_t)row0 * ostride + ocol + n0) = v0;
        if (row1 < M) *(ushort4*)(obase + (size_t)row1 * ostride + ocol + n0) = v1;
    }
}

// ---------- kernel 2: attention v3 — fully register-resident, zero LDS, zero barriers ----------
// Swapped QK^T: sc = mfma(K_frag, Q_frag) -> lane(quad,l16) reg r = S[key=kt*16+quad*4+r][q=l16].
// Softmax per lane over 4*K4 values + 2 shuffles (xor16/32 across quads) -- was 32 shuffles/tile.
// P stays in registers: its (kt,r) layout IS the mfma k-slot permutation pi(quad,j)=(j>>2)*16+quad*4+(j&3)
// (bijective per 32-token group), matched by V gathered as V[pi(slot)][d=l16] -> mfma(V,P) = exact PV.
// PV output: lane holds 4 consecutive dims of one row -> one 8B store.
// K/V frags gathered once per wave from global (L1/L2-shared across the block's 8 heads).
template<int K4>
__device__ __forceinline__ void attn_body(
    unsigned short* __restrict__ qa,
    const unsigned short* __restrict__ kv,
    int n, int base, int M, int h, int quad, int l16)
{
    // K frags (A of QK^T): lane(quad,l16) = K[base+kt*16+l16][h*16+quad*8+j], quad<2 (head_dim 16 pad 32)
    bf16x8 kf[K4];
    #pragma unroll
    for (int kt = 0; kt < K4; ++kt) {
        kf[kt] = (bf16x8)(__bf16)0.0f;
        if (quad < 2) {
            int kr = base + kt * 16 + l16;
            kr = kr < M ? kr : M - 1;      // clamped rows feed masked keys only
            kf[kt] = *(const bf16x8*)(kv + (size_t)kr * 256 + h * 16 + quad * 8);
        }
    }
    // V frags (A of PV): elem j of group g = V[base + g*32 + pi(quad,j)][h*16 + l16]
    bf16x8 vA[K4 / 2];
    #pragma unroll
    for (int g = 0; g < K4 / 2; ++g)
        #pragma unroll
        for (int j = 0; j < 8; ++j) {
            int vr = base + g * 32 + ((j >> 2) * 16) + quad * 4 + (j & 3);
            vr = vr < M ? vr : M - 1;      // P=0 for invalid keys kills garbage (finite) V
            vA[g][j] = ((const __bf16*)kv)[(size_t)vr * 256 + 128 + h * 16 + l16];
        }
    // validity threshold: key kt*16+quad*4+r valid iff r < thr[kt]
    int thr[K4];
    #pragma unroll
    for (int kt = 0; kt < K4; ++kt) {
        int t = n - kt * 16 - quad * 4;
        thr[kt] = t < 0 ? 0 : (t > 4 ? 4 : t);
    }
    const float SC2 = 0.25f * 1.44269504088896340736f;   // 1/sqrt(16) in log2 domain
    const int nqt = (n + 15) >> 4;

    int qr0 = base + l16; qr0 = qr0 < M ? qr0 : M - 1;
    bf16x8 qf = (bf16x8)(__bf16)0.0f;
    if (quad < 2) qf = *(const bf16x8*)(qa + (size_t)qr0 * 128 + h * 16 + quad * 8);

    for (int mt = 0; mt < nqt; ++mt) {
        bf16x8 qn = (bf16x8)(__bf16)0.0f;               // prefetch next Q tile
        if (mt + 1 < nqt && quad < 2) {
            int qr = base + (mt + 1) * 16 + l16;
            qr = qr < M ? qr : M - 1;
            qn = *(const bf16x8*)(qa + (size_t)qr * 128 + h * 16 + quad * 8);
        }
        float pr[K4][4];
        float mm = -3.0e38f;                             // max over ALL (incl. garbage) is exact:
        #pragma unroll                                   // any finite mm >= valid-max cancels in softmax
        for (int kt = 0; kt < K4; ++kt) {
            f32x4 sc = __builtin_amdgcn_mfma_f32_16x16x32_bf16(
                kf[kt], qf, (f32x4){0.f, 0.f, 0.f, 0.f}, 0, 0, 0);
            #pragma unroll
            for (int r = 0; r < 4; ++r) {
                float v = sc[r] * SC2;
                pr[kt][r] = v;
                mm = fmaxf(mm, v);
            }
        }
        mm = fmaxf(mm, __shfl_xor(mm, 16));
        mm = fmaxf(mm, __shfl_xor(mm, 32));
        float ll = 0.f;
        #pragma unroll
        for (int kt = 0; kt < K4; ++kt)
            #pragma unroll
            for (int r = 0; r < 4; ++r) {
                float e = exp2f(pr[kt][r] - mm);
                e = (r < thr[kt]) ? e : 0.f;             // zero invalid keys post-exp
                pr[kt][r] = e;
                ll += e;
            }
        ll += __shfl_xor(ll, 16);
        ll += __shfl_xor(ll, 32);
        float inv = __builtin_amdgcn_rcpf(ll);
        bf16x8 pf[K4 / 2];                               // pack P in pi-matched slot order
        #pragma unroll
        for (int g = 0; g < K4 / 2; ++g)
            #pragma unroll
            for (int j = 0; j < 8; ++j)
                pf[g][j] = (__bf16)(pr[2 * g + (j >> 2)][j & 3] * inv);
        f32x4 o = __builtin_amdgcn_mfma_f32_16x16x32_bf16(
            vA[0], pf[0], (f32x4){0.f, 0.f, 0.f, 0.f}, 0, 0, 0);
        if (K4 == 4)
            o = __builtin_amdgcn_mfma_f32_16x16x32_bf16(vA[1], pf[1], o, 0, 0, 0);
        const int row = mt * 16 + l16;
        if (row < n) {                                   // O[q=l16][d=h*16+quad*4+r]: one 8B store
            ushort4 w;
            w.x = f2bf(o[0]); w.y = f2bf(o[1]); w.z = f2bf(o[2]); w.w = f2bf(o[3]);
            *(ushort4*)(qa + (size_t)(base + row) * 128 + h * 16 + quad * 4) = w;
        }
        qf = qn;
    }
}

__launch_bounds__(512, 6)
__global__ void attn(unsigned short* __restrict__ qa,       // in: Q [M][128]; out: attn (same buf)
                     const unsigned short* __restrict__ kv, // [M][256] K|V
                     const int* __restrict__ agents,
                     const int* __restrict__ offs,
                     int M) {
    const int s = blockIdx.x;
    const int n = agents[s];
    const int base = offs[s];
    const int tid = threadIdx.x;
    const int h = tid >> 6, lane = tid & 63, quad = (lane >> 4), l16 = lane & 15;
    (void)lane;
    if (n > 32) attn_body<4>(qa, kv, n, base, M, h, quad, l16);
    else        attn_body<2>(qa, kv, n, base, M, h, quad, l16);
}

// ---------- kernel 3: out-proj GEMM (unchanged from round 3) ----------
__launch_bounds__(256, 4)
__global__ void oproj(const unsigned short* __restrict__ attn_b,  // [M][128] bf16 (ws)
                      const unsigned short* __restrict__ woutb,
                      const float* __restrict__ bout,
                      float* __restrict__ out, int M) {
    __shared__ __align__(16) unsigned short Ws[128 * 136];   // 34816 B
    __shared__ __align__(16) float biass[128];
    const int m0 = blockIdx.x * 64;
    const int tid = threadIdx.x;

    for (int f = tid; f < 2048; f += 256) {
        int t = f >> 4, c = f & 15;
        *(uint4*)&Ws[t * 136 + c * 8] = *(const uint4*)(woutb + (size_t)t * 128 + c * 8);
    }
    if (tid < 32)
        ((float4*)biass)[tid] = ((const float4*)bout)[tid];
    __syncthreads();                                  // the ONLY barrier

    const int wave = tid >> 6, lane = tid & 63, quad = lane >> 4, l16 = lane & 15;
    const int mw = m0 + wave * 16;                   // each wave: 16 rows

    bf16x8 af[4];
    {
        int row = mw + l16;
        row = (row < M) ? row : (M - 1);
        #pragma unroll
        for (int ks = 0; ks < 4; ++ks)
            af[ks] = *(const bf16x8*)(attn_b + (size_t)row * DM + ks * 32 + quad * 8);
    }

    const int row0 = mw + l16;

    for (int ct = 0; ct < 8; ++ct) {
        bf16x8 bc[4];
        #pragma unroll
        for (int ks = 0; ks < 4; ++ks)
            bc[ks] = *(const bf16x8*)&Ws[(ct * 16 + l16) * 136 + ks * 32 + quad * 8];
        f32x4 a0 = {0.f, 0.f, 0.f, 0.f};
        #pragma unroll
        for (int ks = 0; ks < 4; ++ks)
            a0 = __builtin_amdgcn_mfma_f32_16x16x32_bf16(bc[ks], af[ks], a0, 0, 0, 0);
        const int n0 = ct * 16 + quad * 4;
        const float4 b4 = *(const float4*)(biass + n0);
        float4 o0;
        o0.x = a0[0] + b4.x; o0.y = a0[1] + b4.y; o0.z = a0[2] + b4.z; o0.w = a0[3] + b4.w;
        if (row0 < M) *(float4*)(out + (size_t)row0 * DM + n0) = o0;
    }
}

extern "C" void kernel_launch(void* const* d_in, const int* in_sizes, int n_in,
                              void* d_out, int out_size, void* d_ws, size_t ws_size,
                              hipStream_t stream) {
    const float* att_in     = (const float*)d_in[0];
    const float* in_proj_w  = (const float*)d_in[1];
    const float* in_proj_b  = (const float*)d_in[2];
    const float* out_proj_w = (const float*)d_in[3];
    const float* out_proj_b = (const float*)d_in[4];
    const int*   agents     = (const int*)d_in[5];
    const int B = in_sizes[5];
    const int M = out_size / DM;             // total tokens (66560)

    // ws layout:
    //   [0,8192)            offs
    //   [8192,106496)       wqkv bf16
    //   [106496,139264)     wout bf16
    //   [139264, +M*256)    Q bf16, later attn_out bf16 (overwritten in-place by attn)
    int* offs = (int*)d_ws;
    unsigned short* wqkv_bf = (unsigned short*)((char*)d_ws + 8192);
    unsigned short* wout_bf = (unsigned short*)((char*)d_ws + 106496);
    unsigned short* qbuf    = (unsigned short*)((char*)d_ws + 139264);
    unsigned short* kvbuf   = (unsigned short*)d_out;   // [M][256] bf16 == exactly out bytes

    const int strips = (M + 127) / 128;

    hipLaunchKernelGGL(prep, dim3(65), dim3(256), 0, stream,
                       agents, B, in_proj_w, out_proj_w, offs, wqkv_bf, wout_bf);
    hipLaunchKernelGGL(qkv_gemm, dim3(strips * 3), dim3(256), 0, stream,
                       att_in, wqkv_bf, in_proj_b, qbuf, kvbuf, M);
    hipLaunchKernelGGL(attn, dim3(B), dim3(512), 0, stream,
                       qbuf, kvbuf, agents, offs, M);
    hipLaunchKernelGGL(oproj, dim3((M + 63) / 64), dim3(256), 0, stream,
                       qbuf, wout_bf, out_proj_b, (float*)d_out, M);
}

// Round 5
// 149.008 us; speedup vs baseline: 1.3966x; 1.0670x over previous
//
#include <hip/hip_runtime.h>

#define DM 128
#define NHEADS 8

typedef __attribute__((ext_vector_type(8))) __bf16 bf16x8;
typedef __attribute__((ext_vector_type(8))) unsigned short u16x8;
typedef __attribute__((ext_vector_type(4))) float f32x4;

__device__ inline unsigned short f2bf(float f) {
    unsigned u = __float_as_uint(f);
    u += 0x7FFFu + ((u >> 16) & 1u);
    return (unsigned short)(u >> 16);
}

// ---------- prep: weight->bf16 conversion (blocks 0..63) + offset scan (block 64) ----------
__global__ void prep(const int* __restrict__ agents, int B,
                     const float* __restrict__ wqkv, const float* __restrict__ wout,
                     int* __restrict__ offs,
                     unsigned short* __restrict__ wqkv_bf,
                     unsigned short* __restrict__ wout_bf) {
    if (blockIdx.x < 64) {
        int idx = (blockIdx.x * 256 + threadIdx.x) * 4;   // 0..65532
        if (idx < 49152) {
            float4 v = *(const float4*)(wqkv + idx);
            ushort4 o;
            o.x = f2bf(v.x); o.y = f2bf(v.y); o.z = f2bf(v.z); o.w = f2bf(v.w);
            *(ushort4*)(wqkv_bf + idx) = o;
        } else {
            int j = idx - 49152;
            float4 v = *(const float4*)(wout + j);
            ushort4 o;
            o.x = f2bf(v.x); o.y = f2bf(v.y); o.z = f2bf(v.z); o.w = f2bf(v.w);
            *(ushort4*)(wout_bf + j) = o;
        }
    } else {
        __shared__ int part[256];
        const int tid = threadIdx.x;
        const int per = (B + 255) >> 8;
        const int base = tid * per;
        int s = 0;
        for (int i = 0; i < per; ++i) {
            int idx = base + i;
            if (idx < B) s += agents[idx];
        }
        part[tid] = s;
        __syncthreads();
        for (int off = 1; off < 256; off <<= 1) {
            int v = (tid >= off) ? part[tid - off] : 0;
            __syncthreads();
            part[tid] += v;
            __syncthreads();
        }
        int run = (tid == 0) ? 0 : part[tid - 1];
        for (int i = 0; i < per; ++i) {
            int idx = base + i;
            if (idx < B) { offs[idx] = run; run += agents[idx]; }
        }
    }
}

// ---------- fused kernel: QKV GEMM -> attention -> out-proj, one block per sample ----------
// 512 threads = 8 waves = 1 wave per head. n <= 64 rows per sample.
// LDS: Xs[64][136] bf16 (input tile; later reused as Os, the O exchange buffer)
//      Vs[64][136] bf16 (V tile for the pi-gather). Total 34816 B -> LDS allows 4 blk/CU.
// Q and K never touch LDS: the GEMM D-layout (lane=token, regs=4 dims at quad*4) is
// converted to the A/B-frag layout (lane l16=token, 8 dims at quad*8, quad<2) by 4 shfls:
//   target (quad'<2, l16) dims 8q'..8q'+7 = source quads {2q', 2q'+1} dwords at same l16.
// All MFMA orientations identical to the r3/r4 passing kernels:
//   GEMM:  mfma(Wfrag, Xfrag) -> reg axis = out-col, lane = token row.
//   QK^T:  mfma(kf, qf)       -> reg axis = key (kt*16+quad*4+r), lane = query l16.
//   PV:    mfma(vA, pf)       -> k-slot->key map pi(k)=g*32+((k&7)>>2)*16+(k>>3)*4+(k&3)
//          identical on both operands (bijective per 32-key group); reg axis = head dim.
template<int NT>
__device__ __forceinline__ void fused_body(
    const unsigned short* __restrict__ wqkvb, const float* __restrict__ bqkv,
    const unsigned short* __restrict__ woutb, const float* __restrict__ bout,
    float* __restrict__ out,
    unsigned short* __restrict__ Xs, unsigned short* __restrict__ Vs,
    int n, int base, int h, int quad, int l16)
{
    constexpr int G   = (NT + 1) / 2;   // 32-key PV groups
    constexpr int KT2 = 2 * G;          // padded 16-key tile count
    bf16x8 qf[NT], kf[NT];
    const int shA = (quad & 1) * 32 + l16;   // shfl sources for frag rebuild
    const int shB = shA + 16;

    // ---- QKV GEMM (per wave: the 16 Q, K, V columns of head h) ----
    #pragma unroll
    for (int seg = 0; seg < 3; ++seg) {
        bf16x8 wf[4];
        #pragma unroll
        for (int ks = 0; ks < 4; ++ks)
            wf[ks] = *(const bf16x8*)(wqkvb +
                     (size_t)(seg * 128 + h * 16 + l16) * 128 + ks * 32 + quad * 8);
        const float4 bs = *(const float4*)(bqkv + seg * 128 + h * 16 + quad * 4);
        #pragma unroll
        for (int mt = 0; mt < NT; ++mt) {
            f32x4 acc = {0.f, 0.f, 0.f, 0.f};
            #pragma unroll
            for (int ks = 0; ks < 4; ++ks) {
                bf16x8 xf = *(const bf16x8*)&Xs[(mt * 16 + l16) * 136 + ks * 32 + quad * 8];
                acc = __builtin_amdgcn_mfma_f32_16x16x32_bf16(wf[ks], xf, acc, 0, 0, 0);
            }
            ushort4 w;
            w.x = f2bf(acc[0] + bs.x); w.y = f2bf(acc[1] + bs.y);
            w.z = f2bf(acc[2] + bs.z); w.w = f2bf(acc[3] + bs.w);
            if (seg == 2) {            // V -> LDS row-major (read back via pi-gather)
                *(ushort4*)&Vs[(mt * 16 + l16) * 136 + h * 16 + quad * 4] = w;
            } else {                   // Q/K -> registers via 4-shfl layout rebuild
                unsigned u0 = (unsigned)w.x | ((unsigned)w.y << 16);
                unsigned u1 = (unsigned)w.z | ((unsigned)w.w << 16);
                uint4 q;
                q.x = __shfl(u0, shA); q.y = __shfl(u1, shA);
                q.z = __shfl(u0, shB); q.w = __shfl(u1, shB);
                bf16x8 fr = (quad < 2) ? __builtin_bit_cast(bf16x8, q)
                                       : (bf16x8)(__bf16)0.0f;
                if (seg == 0) qf[mt] = fr; else kf[mt] = fr;
            }
        }
    }

    // vA gather from Vs (same-wave data; rows >= NT*16 are the zero-fill)
    bf16x8 vA[G];
    const __bf16* Vsb = (const __bf16*)Vs;
    #pragma unroll
    for (int g = 0; g < G; ++g)
        #pragma unroll
        for (int j = 0; j < 8; ++j)
            vA[g][j] = Vsb[(size_t)(g * 32 + ((j >> 2) * 16) + quad * 4 + (j & 3)) * 136
                           + h * 16 + l16];

    __syncthreads();   // all Xs GEMM reads done -> Os (=Xs) becomes writable

    int thr[KT2];      // key kt*16+quad*4+r valid iff r < thr[kt]
    #pragma unroll
    for (int kt = 0; kt < KT2; ++kt) {
        int t = n - kt * 16 - quad * 4;
        thr[kt] = t < 0 ? 0 : (t > 4 ? 4 : t);
    }
    const float SC2 = 0.25f * 1.44269504088896340736f;   // 1/sqrt(16), log2 domain
    unsigned short* Os = Xs;

    #pragma unroll
    for (int mt = 0; mt < NT; ++mt) {
        float pr[KT2][4];
        float mm = -3.0e38f;   // max over all (incl. finite garbage) keys: exact in softmax
        #pragma unroll
        for (int kt = 0; kt < KT2; ++kt) {
            if (kt < NT) {
                f32x4 sc = __builtin_amdgcn_mfma_f32_16x16x32_bf16(
                    kf[kt], qf[mt], (f32x4){0.f, 0.f, 0.f, 0.f}, 0, 0, 0);
                #pragma unroll
                for (int r = 0; r < 4; ++r) {
                    float v = sc[r] * SC2;
                    pr[kt][r] = v;
                    mm = fmaxf(mm, v);
                }
            } else {
                #pragma unroll
                for (int r = 0; r < 4; ++r) pr[kt][r] = -3.0e38f;
            }
        }
        mm = fmaxf(mm, __shfl_xor(mm, 16));
        mm = fmaxf(mm, __shfl_xor(mm, 32));
        float ll = 0.f;
        #pragma unroll
        for (int kt = 0; kt < KT2; ++kt)
            #pragma unroll
            for (int r = 0; r < 4; ++r) {
                float e = exp2f(pr[kt][r] - mm);
                e = (r < thr[kt]) ? e : 0.f;
                pr[kt][r] = e;
                ll += e;
            }
        ll += __shfl_xor(ll, 16);
        ll += __shfl_xor(ll, 32);
        float inv = __builtin_amdgcn_rcpf(ll);
        bf16x8 pf[G];
        #pragma unroll
        for (int g = 0; g < G; ++g)
            #pragma unroll
            for (int j = 0; j < 8; ++j)
                pf[g][j] = (__bf16)(pr[2 * g + (j >> 2)][j & 3] * inv);
        f32x4 o = __builtin_amdgcn_mfma_f32_16x16x32_bf16(
            vA[0], pf[0], (f32x4){0.f, 0.f, 0.f, 0.f}, 0, 0, 0);
        if constexpr (G == 2)
            o = __builtin_amdgcn_mfma_f32_16x16x32_bf16(vA[1], pf[1], o, 0, 0, 0);
        const int row = mt * 16 + l16;
        if (row < n) {   // O[q=row][d=h*16+quad*4+r] -> one 8B LDS store
            ushort4 w;
            w.x = f2bf(o[0]); w.y = f2bf(o[1]); w.z = f2bf(o[2]); w.w = f2bf(o[3]);
            *(ushort4*)&Os[row * 136 + h * 16 + quad * 4] = w;
        }
    }
    __syncthreads();   // all heads' O slices visible

    // ---- out-proj: wave h computes out cols h*16..h*16+15 for all rows ----
    bf16x8 wf2[4];
    #pragma unroll
    for (int ks = 0; ks < 4; ++ks)
        wf2[ks] = *(const bf16x8*)(woutb +
                  (size_t)(h * 16 + l16) * 128 + ks * 32 + quad * 8);
    const float4 bo = *(const float4*)(bout + h * 16 + quad * 4);
    #pragma unroll
    for (int mt = 0; mt < NT; ++mt) {
        const int row = mt * 16 + l16;
        f32x4 acc = {0.f, 0.f, 0.f, 0.f};
        #pragma unroll
        for (int ks = 0; ks < 4; ++ks) {
            bf16x8 af = *(const bf16x8*)&Os[row * 136 + ks * 32 + quad * 8];
            acc = __builtin_amdgcn_mfma_f32_16x16x32_bf16(wf2[ks], af, acc, 0, 0, 0);
        }
        if (row < n) {
            float4 o;
            o.x = acc[0] + bo.x; o.y = acc[1] + bo.y;
            o.z = acc[2] + bo.z; o.w = acc[3] + bo.w;
            *(float4*)(out + (size_t)(base + row) * DM + h * 16 + quad * 4) = o;
        }
    }
}

#define XS_OFF 0
#define VS_OFF 17408
#define SMEMF  34816

__launch_bounds__(512, 4)
__global__ void fused(const float* __restrict__ x,
                      const unsigned short* __restrict__ wqkvb,
                      const float* __restrict__ bqkv,
                      const unsigned short* __restrict__ woutb,
                      const float* __restrict__ bout,
                      float* __restrict__ out,
                      const int* __restrict__ agents,
                      const int* __restrict__ offs) {
    __shared__ __align__(16) char smem[SMEMF];
    unsigned short* Xs = (unsigned short*)(smem + XS_OFF);
    unsigned short* Vs = (unsigned short*)(smem + VS_OFF);

    const int s = blockIdx.x;
    const int n = agents[s];
    const int base = offs[s];
    const int tid = threadIdx.x;
    const int h = tid >> 6, lane = tid & 63, quad = lane >> 4, l16 = lane & 15;

    // zero Vs (vA can touch rows up to G*32 > NT*16 when NT is odd)
    for (int f = tid; f < 1088; f += 512)
        ((uint4*)(smem + VS_OFF))[f] = make_uint4(0u, 0u, 0u, 0u);
    // stage X rows -> Xs bf16, zero-pad rows >= n (Os rows >= n stay zero, masked later)
    for (int f = tid; f < 2048; f += 512) {
        int t = f >> 5, c = f & 31;
        ushort4 o = make_ushort4(0, 0, 0, 0);
        if (t < n) {
            float4 v = *(const float4*)(x + (size_t)(base + t) * DM + c * 4);
            o.x = f2bf(v.x); o.y = f2bf(v.y); o.z = f2bf(v.z); o.w = f2bf(v.w);
        }
        *(ushort4*)&Xs[t * 136 + c * 4] = o;
    }
    __syncthreads();

    const int nkt = (n + 15) >> 4;   // block-uniform -> barriers inside are safe
    if      (nkt == 1) fused_body<1>(wqkvb, bqkv, woutb, bout, out, Xs, Vs, n, base, h, quad, l16);
    else if (nkt == 2) fused_body<2>(wqkvb, bqkv, woutb, bout, out, Xs, Vs, n, base, h, quad, l16);
    else if (nkt == 3) fused_body<3>(wqkvb, bqkv, woutb, bout, out, Xs, Vs, n, base, h, quad, l16);
    else               fused_body<4>(wqkvb, bqkv, woutb, bout, out, Xs, Vs, n, base, h, quad, l16);
}

extern "C" void kernel_launch(void* const* d_in, const int* in_sizes, int n_in,
                              void* d_out, int out_size, void* d_ws, size_t ws_size,
                              hipStream_t stream) {
    const float* att_in     = (const float*)d_in[0];
    const float* in_proj_w  = (const float*)d_in[1];
    const float* in_proj_b  = (const float*)d_in[2];
    const float* out_proj_w = (const float*)d_in[3];
    const float* out_proj_b = (const float*)d_in[4];
    const int*   agents     = (const int*)d_in[5];
    const int B = in_sizes[5];

    // ws layout: [0,8192) offs | [8192,106496) wqkv bf16 | [106496,139264) wout bf16
    int* offs = (int*)d_ws;
    unsigned short* wqkv_bf = (unsigned short*)((char*)d_ws + 8192);
    unsigned short* wout_bf = (unsigned short*)((char*)d_ws + 106496);

    hipLaunchKernelGGL(prep, dim3(65), dim3(256), 0, stream,
                       agents, B, in_proj_w, out_proj_w, offs, wqkv_bf, wout_bf);
    hipLaunchKernelGGL(fused, dim3(B), dim3(512), 0, stream,
                       att_in, wqkv_bf, in_proj_b, wout_bf, out_proj_b,
                       (float*)d_out, agents, offs);
}